// Round 6
// baseline (150.697 us; speedup 1.0000x reference)
//
#include <hip/hip_runtime.h>
#include <hip/hip_bf16.h>

// Problem constants (fixed by setup_inputs): C=64 cliques, S=16, D=256, P=65536
#define NC 64
#define NS 16
#define ND 256
#define NP 65536
#define EPS 1e-8f

typedef float f4 __attribute__((ext_vector_type(4)));

// ---------------------------------------------------------------------------
// Fused kernel: each block (chunk, c) recomputes clique c's 16x16 attention
// weights (cheap, L2-resident reps) and then streams its 1024-wide p-chunk:
//   out[c,i,p] = sum_j w[c,i,j] * params[c,j,p]
//
// Weight prelude (redundant 64x per clique, ~2 us aggregate at L2 BW):
//   thread t = i*16 + j computes dot(x_i, x_j) from LDS-staged reps;
//   row softmax via __shfl_xor within the 16-lane group (offsets 1,2,4,8
//   stay inside the group on wave64).
//
// Aggregation: each thread owns 4 consecutive p's (float4). Non-temporal
// loads/stores — pure read-once/write-once streaming, skip cache allocation.
// ---------------------------------------------------------------------------
__global__ __launch_bounds__(256) void coexpert_fused(
    const float* __restrict__ reps,   // [C, S, D]
    const float* __restrict__ params, // [C, S, P]
    float* __restrict__ out)          // [C, S, P]
{
    const int chunk = blockIdx.x;     // 64 chunks of 1024 p's
    const int c     = blockIdx.y;     // 64 cliques
    const int t     = threadIdx.x;

    __shared__ float xs[NS][ND];      // 16 KiB staged reps
    __shared__ float norms[NS];
    __shared__ float ws[NS][NS];      // 1 KiB weights

    // --- Prelude: attention weights for clique c ---------------------------
    // Cooperative reps load: 4096 floats = 1024 float4; 4 per thread.
    // Normal (cacheable) loads: 64 blocks share each clique's reps via L2.
    {
        const f4* xc  = reinterpret_cast<const f4*>(reps + (size_t)c * NS * ND);
        f4*       xsv = reinterpret_cast<f4*>(&xs[0][0]);
        #pragma unroll
        for (int k = 0; k < 4; ++k)
            xsv[t + 256 * k] = xc[t + 256 * k];
    }
    __syncthreads();

    const int i = t >> 4;
    const int j = t & 15;

    float dot = 0.f;
    #pragma unroll 8
    for (int d = 0; d < ND; d += 4) {
        f4 a = *reinterpret_cast<const f4*>(&xs[i][d]);
        f4 b = *reinterpret_cast<const f4*>(&xs[j][d]);
        dot += a.x * b.x + a.y * b.y + a.z * b.z + a.w * b.w;
    }

    if (i == j) norms[i] = sqrtf(dot);
    __syncthreads();

    float sim = dot / (norms[i] * norms[j] + EPS);

    // Row softmax over j: 16-lane-group butterfly (offsets 1,2,4,8).
    float m = sim;
    #pragma unroll
    for (int off = 1; off < 16; off <<= 1)
        m = fmaxf(m, __shfl_xor(m, off));
    float e = expf(sim - m);
    float s = e;
    #pragma unroll
    for (int off = 1; off < 16; off <<= 1)
        s += __shfl_xor(s, off);

    ws[i][j] = e / s;
    __syncthreads();

    // --- Streaming aggregation ---------------------------------------------
    const size_t base = (size_t)c * NS * NP + (size_t)chunk * 1024 + (size_t)t * 4;
    const f4* pin  = reinterpret_cast<const f4*>(params + base);  // stride NP/4 f4's
    f4*       pout = reinterpret_cast<f4*>(out + base);

    f4 v[NS];
    #pragma unroll
    for (int jj = 0; jj < NS; ++jj)
        v[jj] = __builtin_nontemporal_load(pin + (size_t)jj * (NP / 4));

    #pragma unroll
    for (int ii = 0; ii < NS; ++ii) {
        f4 acc = (f4)(0.f);
        #pragma unroll
        for (int jj = 0; jj < NS; ++jj)
            acc += ws[ii][jj] * v[jj];   // LDS broadcast, conflict-free
        __builtin_nontemporal_store(acc, pout + (size_t)ii * (NP / 4));
    }
}

extern "C" void kernel_launch(void* const* d_in, const int* in_sizes, int n_in,
                              void* d_out, int out_size, void* d_ws, size_t ws_size,
                              hipStream_t stream) {
    const float* reps   = (const float*)d_in[0];   // [64,16,256]   f32
    const float* params = (const float*)d_in[1];   // [64,16,65536] f32
    float* out = (float*)d_out;                    // [64,16,65536] f32

    dim3 grid(NP / 1024, NC);                      // (64, 64)
    hipLaunchKernelGGL(coexpert_fused, grid, dim3(256), 0, stream,
                       reps, params, out);
}

// Round 7
// 91.207 us; speedup vs baseline: 1.6523x; 1.6523x over previous
//
#include <hip/hip_runtime.h>
#include <hip/hip_bf16.h>

// Problem constants (fixed by setup_inputs): C=64 cliques, S=16, D=256, P=65536
#define NC 64
#define NS 16
#define ND 256
#define NDP (ND + 4)   // padded LDS row: 260 floats -> bank(j*260+d)%32 = (j*4+d)%32,
                       // 2-way max across 16 rows = free (m136). Row stride 1040 B is
                       // 16B-aligned so f4 reads stay legal.
#define NP 65536
#define EPS 1e-8f

typedef float f4 __attribute__((ext_vector_type(4)));

// ---------------------------------------------------------------------------
// Kernel 1: per-clique cosine-similarity attention weights.
// One block per clique, 256 threads; thread t = i*16 + j computes dot(x_i,x_j).
// Row softmax via __shfl_xor within the 16-lane group.
// ---------------------------------------------------------------------------
__global__ __launch_bounds__(256) void coexpert_weights(
    const float* __restrict__ reps,   // [C, S, D]
    float* __restrict__ w)            // [C, S, S]
{
    const int c = blockIdx.x;
    const int t = threadIdx.x;

    __shared__ float xs[NS][NDP];     // padded: conflict-free column reads
    __shared__ float norms[NS];

    // Cooperative load of this clique's reps: 4096 floats / 256 threads.
    const float* xc = reps + (size_t)c * NS * ND;
    #pragma unroll
    for (int k = t; k < NS * ND; k += 256)
        xs[k >> 8][k & (ND - 1)] = xc[k];
    __syncthreads();

    const int i = t >> 4;
    const int j = t & 15;

    // dot(x_i, x_j): xs[i][*] is a 16-lane broadcast (free); xs[j][*] is
    // 2-way bank aliased under the +4 pad (free).
    float dot = 0.f;
    #pragma unroll 8
    for (int d = 0; d < ND; d += 4) {
        f4 a = *reinterpret_cast<const f4*>(&xs[i][d]);
        f4 b = *reinterpret_cast<const f4*>(&xs[j][d]);
        dot += a.x * b.x + a.y * b.y + a.z * b.z + a.w * b.w;
    }

    // Diagonal threads publish norms.
    if (i == j) norms[i] = sqrtf(dot);
    __syncthreads();

    float sim = dot / (norms[i] * norms[j] + EPS);

    // Row softmax over j (16-lane group butterfly; offsets 1,2,4,8).
    float m = sim;
    #pragma unroll
    for (int off = 1; off < 16; off <<= 1)
        m = fmaxf(m, __shfl_xor(m, off));
    float e = expf(sim - m);
    float s = e;
    #pragma unroll
    for (int off = 1; off < 16; off <<= 1)
        s += __shfl_xor(s, off);

    w[(size_t)c * NS * NS + t] = e / s;
}

// ---------------------------------------------------------------------------
// Kernel 2: out[c,i,p] = sum_j w[c,i,j] * params[c,j,p]
// Streaming. Cache-policy experiment this round:
//   loads  = NORMAL (allocate): params (256 MB) exactly fits the 256 MiB
//            Infinity Cache -> steady-state replays read mostly from L3.
//   stores = NON-TEMPORAL (no-allocate): out writes must not evict params.
// ---------------------------------------------------------------------------
__global__ __launch_bounds__(256) void coexpert_agg(
    const float* __restrict__ params, // [C, S, P]
    const float* __restrict__ w,      // [C, S, S]
    float* __restrict__ out)          // [C, S, P]
{
    const int chunk = blockIdx.x;     // 64 chunks of 1024 p's
    const int c     = blockIdx.y;     // 64 cliques
    const int t     = threadIdx.x;

    __shared__ float ws[NS][NS];
    ws[t >> 4][t & 15] = w[(size_t)c * NS * NS + t];
    __syncthreads();

    const size_t base = (size_t)c * NS * NP + (size_t)chunk * 1024 + (size_t)t * 4;
    const f4* pin  = reinterpret_cast<const f4*>(params + base);  // stride NP/4 f4's
    f4*       pout = reinterpret_cast<f4*>(out + base);

    f4 v[NS];
    #pragma unroll
    for (int j = 0; j < NS; ++j)
        v[j] = pin[(size_t)j * (NP / 4)];     // normal cacheable load

    #pragma unroll
    for (int i = 0; i < NS; ++i) {
        f4 acc = (f4)(0.f);
        #pragma unroll
        for (int j = 0; j < NS; ++j)
            acc += ws[i][j] * v[j];           // LDS broadcast, conflict-free
        __builtin_nontemporal_store(acc, pout + (size_t)i * (NP / 4));
    }
}

extern "C" void kernel_launch(void* const* d_in, const int* in_sizes, int n_in,
                              void* d_out, int out_size, void* d_ws, size_t ws_size,
                              hipStream_t stream) {
    const float* reps   = (const float*)d_in[0];   // [64,16,256]   f32
    const float* params = (const float*)d_in[1];   // [64,16,65536] f32
    float* out = (float*)d_out;                    // [64,16,65536] f32
    float* w   = (float*)d_ws;                     // [64,16,16]    f32 scratch (4 KiB)

    hipLaunchKernelGGL(coexpert_weights, dim3(NC), dim3(256), 0, stream, reps, w);

    dim3 grid(NP / 1024, NC);                      // (64, 64)
    hipLaunchKernelGGL(coexpert_agg, grid, dim3(256), 0, stream, params, w, out);
}

// Round 8
// 91.123 us; speedup vs baseline: 1.6538x; 1.0009x over previous
//
#include <hip/hip_runtime.h>
#include <hip/hip_bf16.h>

// Problem constants (fixed by setup_inputs): C=64 cliques, S=16, D=256, P=65536
#define NC 64
#define NS 16
#define ND 256
#define NDP (ND + 4)   // padded LDS row: 260 floats. Column read xs[j][d] across
                       // j=0..15 hits bank (j*4+d)%32 -> 2-way alias = free (m136).
                       // Row stride 1040 B stays 16B-aligned for f4 access.
#define NP 65536
#define EPS 1e-8f

typedef float f4 __attribute__((ext_vector_type(4)));

// ---------------------------------------------------------------------------
// Fused kernel, v2 (round-6 retry with the bank-conflict fix).
// Block (chunk, c): recompute clique c's 16x16 attention weights from
// L2-resident reps (padded LDS -> no conflicts), then stream the p-chunk:
//   out[c,i,p] = sum_j w[c,i,j] * params[c,j,p]
//
// Load-issue order matters: reps loads are issued FIRST, params loads SECOND,
// prelude compute THIRD. vmcnt counts from the oldest op, so the prelude's
// wait on reps data leaves the 16 params loads in flight — their HBM/L3
// latency hides under the dot-product/softmax compute.
// ---------------------------------------------------------------------------
__global__ __launch_bounds__(256) void coexpert_fused(
    const float* __restrict__ reps,   // [C, S, D]
    const float* __restrict__ params, // [C, S, P]
    float* __restrict__ out)          // [C, S, P]
{
    const int chunk = blockIdx.x;     // 64 chunks of 1024 p's
    const int c     = blockIdx.y;     // 64 cliques
    const int t     = threadIdx.x;

    __shared__ float xs[NS][NDP];     // padded staged reps (~16.6 KiB)
    __shared__ float norms[NS];
    __shared__ float ws[NS][NS];

    // (1) Issue reps loads -> registers (4 x f4 per thread = 16 KiB/block).
    f4 xr[4];
    {
        const f4* xc = reinterpret_cast<const f4*>(reps + (size_t)c * NS * ND);
        #pragma unroll
        for (int m = 0; m < 4; ++m)
            xr[m] = xc[t + 256 * m];
    }

    // (2) Issue params loads (younger than reps loads -> prelude's wait on
    //     reps keeps these in flight). Normal cacheable: params = 256 MiB
    //     exactly fits L3 and stays resident across graph replays.
    const size_t base = (size_t)c * NS * NP + (size_t)chunk * 1024 + (size_t)t * 4;
    const f4* pin  = reinterpret_cast<const f4*>(params + base);
    f4*       pout = reinterpret_cast<f4*>(out + base);

    f4 v[NS];
    #pragma unroll
    for (int jj = 0; jj < NS; ++jj)
        v[jj] = pin[(size_t)jj * (NP / 4)];

    // (3) Prelude: stage reps, cosine-sim, row softmax.
    #pragma unroll
    for (int m = 0; m < 4; ++m) {
        const int q   = t + 256 * m;     // f4 index: 64 f4 per 256-float row
        const int row = q >> 6;
        const int col = (q & 63) << 2;
        *reinterpret_cast<f4*>(&xs[row][col]) = xr[m];
    }
    __syncthreads();

    const int i = t >> 4;
    const int j = t & 15;

    float dot = 0.f;
    #pragma unroll 8
    for (int d = 0; d < ND; d += 4) {
        f4 a = *reinterpret_cast<const f4*>(&xs[i][d]);   // 4-row broadcast
        f4 b = *reinterpret_cast<const f4*>(&xs[j][d]);   // 2-way alias (pad)
        dot += a.x * b.x + a.y * b.y + a.z * b.z + a.w * b.w;
    }

    if (i == j) norms[i] = sqrtf(dot);
    __syncthreads();

    float sim = dot / (norms[i] * norms[j] + EPS);

    // Row softmax over j: 16-lane-group butterfly (offsets 1,2,4,8 stay
    // in-group on wave64).
    float m_ = sim;
    #pragma unroll
    for (int off = 1; off < 16; off <<= 1)
        m_ = fmaxf(m_, __shfl_xor(m_, off));
    float e = expf(sim - m_);
    float s = e;
    #pragma unroll
    for (int off = 1; off < 16; off <<= 1)
        s += __shfl_xor(s, off);

    ws[i][j] = e / s;
    __syncthreads();

    // (4) Mix + non-temporal stores (write-once stream: don't evict params
    //     from L3).
    #pragma unroll
    for (int ii = 0; ii < NS; ++ii) {
        f4 acc = (f4)(0.f);
        #pragma unroll
        for (int jj = 0; jj < NS; ++jj)
            acc += ws[ii][jj] * v[jj];   // LDS broadcast, conflict-free
        __builtin_nontemporal_store(acc, pout + (size_t)ii * (NP / 4));
    }
}

extern "C" void kernel_launch(void* const* d_in, const int* in_sizes, int n_in,
                              void* d_out, int out_size, void* d_ws, size_t ws_size,
                              hipStream_t stream) {
    const float* reps   = (const float*)d_in[0];   // [64,16,256]   f32
    const float* params = (const float*)d_in[1];   // [64,16,65536] f32
    float* out = (float*)d_out;                    // [64,16,65536] f32

    dim3 grid(NP / 1024, NC);                      // (64, 64)
    hipLaunchKernelGGL(coexpert_fused, grid, dim3(256), 0, stream,
                       reps, params, out);
}